// Round 6
// baseline (444.452 us; speedup 1.0000x reference)
//
#include <hip/hip_runtime.h>

// nnmodel_35708358099045 R9: two rows per thread, cross-row pipelined.
// R8 post-mortem: same-chain prefetch moved the wait, didn't hide it (153 vs
// 147 us). R6 datapoint: this memory system sustains 3.4 TB/s when misses
// arrive steadily; R7 sustains only 2.0 TB/s because all waves are phase-
// aligned (chip-wide burst/compute/burst phases -> HBM flood then idle).
// Fix: 2 independent rows per thread (e, e+256). Per iteration issue both
// rows' z-lines, compute row A (covers B's loads in flight), compute row B
// (fully covered). Doubles per-wave MLP + issue density, halves wave count,
// gives every wait an INDEPENDENT compute stream. launch_bounds(256,3)
// caps VGPR ~170 (3 waves/SIMD). FP order per row identical to R5-R8.

#define HN 10
#define ND 40
#define HF 8
#define TPB 256
#define RPT 2              // rows per thread
#define RPB (TPB * RPT)    // 512 rows per block

__global__ __launch_bounds__(TPB, 3) void gnn_kernel(
    const float* __restrict__ x,          // [B, 40]
    const float* __restrict__ z,          // [B, 10, 8]
    const float* __restrict__ y,          // [B, 40]
    const float* __restrict__ enc_rel_w,  // [8, 1]
    const float* __restrict__ enc_rel_b,  // [8]
    const float* __restrict__ enc_root_w, // [8, 8]
    const float* __restrict__ pred_rel_w, // [8, 8]
    const float* __restrict__ pred_rel_b, // [8]
    const float* __restrict__ pred_root_w,// [8, 8]
    const float* __restrict__ dec_rel_w,  // [1, 8]
    const float* __restrict__ dec_rel_b,  // [1]
    const float* __restrict__ dec_root_w, // [1, 1]
    float* __restrict__ out,              // [B, 40]
    int B)
{
    const long long eA = (long long)blockIdx.x * RPB + threadIdx.x;
    const long long eB = eA + TPB;

    const float w = 0.8948393168143698f;  // exp(-(1/3)^2) as fp32

    const float4* xrA = (const float4*)(x + eA * ND);
    const float4* zrA = (const float4*)(z + eA * (HN * HF));
    const float4* yrA = (const float4*)(y + eA * ND);
    float4*       ogA = (float4*)(out + eA * ND);
    const float4* xrB = (const float4*)(x + eB * ND);
    const float4* zrB = (const float4*)(z + eB * (HN * HF));
    const float4* yrB = (const float4*)(y + eB * ND);
    float4*       ogB = (float4*)(out + eB * ND);

    const float drb   = dec_rel_b[0];
    const float droot = dec_root_w[0];

    // encoder GraphConv row: r = relu(agg*erw + erb + z . enc_root_w)
    auto enc_row = [&](float aggv, float4 v0, float4 v1, float (&r)[HF]) {
        float zrow[HF] = {v0.x, v0.y, v0.z, v0.w, v1.x, v1.y, v1.z, v1.w};
        #pragma unroll
        for (int f = 0; f < HF; ++f) {
            float acc = aggv * enc_rel_w[f] + enc_rel_b[f];
            #pragma unroll
            for (int g = 0; g < HF; ++g)
                acc += zrow[g] * enc_root_w[f * HF + g];
            r[f] = fmaxf(acc, 0.0f);
        }
    };

    // predictor + decoder row-dot for center rc with neighbors rm, rp
    auto emit = [&](const float (&rm)[HF], const float (&rc)[HF],
                    const float (&rp)[HF]) -> float {
        float a2[HF];
        #pragma unroll
        for (int f = 0; f < HF; ++f)
            a2[f] = rc[f] + w * (rm[f] + rp[f]);
        float s = 0.0f;
        #pragma unroll
        for (int f = 0; f < HF; ++f) {
            float acc = pred_rel_b[f];
            #pragma unroll
            for (int g = 0; g < HF; ++g)
                acc += a2[g] * pred_rel_w[f * HF + g];
            #pragma unroll
            for (int g = 0; g < HF; ++g)
                acc += rc[g] * pred_root_w[f * HF + g];
            s += fmaxf(acc, 0.0f) * dec_rel_w[f];
        }
        return s;
    };

    auto store_out = [&](float4* og, int idx, float sa, float sb, float4 yv) {
        const float pair = sa + sb + drb;
        float4 o;
        o.x = (sa + drb) + yv.x * droot;
        o.y = pair       + yv.y * droot;
        o.z = pair       + yv.z * droot;
        o.w = (sb + drb) + yv.w * droot;
        og[idx] = o;
    };

    // -------- prologue: one big burst (xA, xB, zA line0, zB line0) --------
    float4 XA0 = xrA[0], XA1 = xrA[1], XA2 = xrA[2], XA3 = xrA[3], XA4 = xrA[4],
           XA5 = xrA[5], XA6 = xrA[6], XA7 = xrA[7], XA8 = xrA[8], XA9 = xrA[9];
    float4 XB0 = xrB[0], XB1 = xrB[1], XB2 = xrB[2], XB3 = xrB[3], XB4 = xrB[4],
           XB5 = xrB[5], XB6 = xrB[6], XB7 = xrB[7], XB8 = xrB[8], XB9 = xrB[9];
    float4 zqA0 = zrA[0], zqA1 = zrA[1], zqA2 = zrA[2], zqA3 = zrA[3];
    float4 zqB0 = zrB[0], zqB1 = zrB[1], zqB2 = zrB[2], zqB3 = zrB[3];

    // aggs row A (frees XA), FP order as R5-R8
    const float aA0 = XA9.y + XA9.z + XA9.w + XA0.x + XA0.y + XA0.z;
    const float aA1 = XA0.y + XA0.z + XA0.w + XA1.x + XA1.y + XA1.z;
    const float aA2 = XA1.y + XA1.z + XA1.w + XA2.x + XA2.y + XA2.z;
    const float aA3 = XA2.y + XA2.z + XA2.w + XA3.x + XA3.y + XA3.z;
    const float aA4 = XA3.y + XA3.z + XA3.w + XA4.x + XA4.y + XA4.z;
    const float aA5 = XA4.y + XA4.z + XA4.w + XA5.x + XA5.y + XA5.z;
    const float aA6 = XA5.y + XA5.z + XA5.w + XA6.x + XA6.y + XA6.z;
    const float aA7 = XA6.y + XA6.z + XA6.w + XA7.x + XA7.y + XA7.z;
    const float aA8 = XA7.y + XA7.z + XA7.w + XA8.x + XA8.y + XA8.z;
    const float aA9 = XA8.y + XA8.z + XA8.w + XA9.x + XA9.y + XA9.z;
    // aggs row B (frees XB)
    const float aB0 = XB9.y + XB9.z + XB9.w + XB0.x + XB0.y + XB0.z;
    const float aB1 = XB0.y + XB0.z + XB0.w + XB1.x + XB1.y + XB1.z;
    const float aB2 = XB1.y + XB1.z + XB1.w + XB2.x + XB2.y + XB2.z;
    const float aB3 = XB2.y + XB2.z + XB2.w + XB3.x + XB3.y + XB3.z;
    const float aB4 = XB3.y + XB3.z + XB3.w + XB4.x + XB4.y + XB4.z;
    const float aB5 = XB4.y + XB4.z + XB4.w + XB5.x + XB5.y + XB5.z;
    const float aB6 = XB5.y + XB5.z + XB5.w + XB6.x + XB6.y + XB6.z;
    const float aB7 = XB6.y + XB6.z + XB6.w + XB7.x + XB7.y + XB7.z;
    const float aB8 = XB7.y + XB7.z + XB7.w + XB8.x + XB8.y + XB8.z;
    const float aB9 = XB8.y + XB8.z + XB8.w + XB9.x + XB9.y + XB9.z;

    // agg queues (nodes 2..9), shifted by 2 per iteration
    float uA0 = aA2, uA1 = aA3, uA2 = aA4, uA3 = aA5,
          uA4 = aA6, uA5 = aA7, uA6 = aA8, uA7 = aA9;
    float uB0 = aB2, uB1 = aB3, uB2 = aB4, uB3 = aB5,
          uB4 = aB6, uB5 = aB7, uB6 = aB8, uB7 = aB9;

    float r0A[HF], r1A[HF], r0B[HF], r1B[HF];
    enc_row(aA0, zqA0, zqA1, r0A);
    enc_row(aA1, zqA2, zqA3, r1A);
    enc_row(aB0, zqB0, zqB1, r0B);
    enc_row(aB1, zqB2, zqB3, r1B);

    float rmA[HF], rcA[HF], rmB[HF], rcB[HF];
    #pragma unroll
    for (int f = 0; f < HF; ++f) { rmA[f] = r0A[f]; rcA[f] = r1A[f];
                                   rmB[f] = r0B[f]; rcB[f] = r1B[f]; }

    // s2[1..8] shift queues
    float tA0 = 0.f, tA1 = 0.f, tA2 = 0.f, tA3 = 0.f,
          tA4 = 0.f, tA5 = 0.f, tA6 = 0.f, tA7 = 0.f;
    float tB0 = 0.f, tB1 = 0.f, tB2 = 0.f, tB3 = 0.f,
          tB4 = 0.f, tB5 = 0.f, tB6 = 0.f, tB7 = 0.f;

    // -------- loop: j=1..4, nodes (2j,2j+1) for both rows ----------------
    // Issue both rows' z-lines back-to-back; row-A compute (~960 cy) covers
    // row-B's loads in flight; row-B compute runs wait-free.
    #pragma unroll 1
    for (int j = 1; j <= 4; ++j) {
        float4 qA0 = zrA[4*j + 0], qA1 = zrA[4*j + 1],
               qA2 = zrA[4*j + 2], qA3 = zrA[4*j + 3];
        float4 qB0 = zrB[4*j + 0], qB1 = zrB[4*j + 1],
               qB2 = zrB[4*j + 2], qB3 = zrB[4*j + 3];

        float rp0A[HF], rp1A[HF];
        enc_row(uA0, qA0, qA1, rp0A);                // node 2j   (row A)
        enc_row(uA1, qA2, qA3, rp1A);                // node 2j+1 (row A)
        const float sAA = emit(rmA, rcA, rp0A);      // s2[2j-1]  (row A)
        const float sBA = emit(rcA, rp0A, rp1A);     // s2[2j]    (row A)

        float rp0B[HF], rp1B[HF];
        enc_row(uB0, qB0, qB1, rp0B);                // node 2j   (row B)
        enc_row(uB1, qB2, qB3, rp1B);                // node 2j+1 (row B)
        const float sAB = emit(rmB, rcB, rp0B);      // s2[2j-1]  (row B)
        const float sBB = emit(rcB, rp0B, rp1B);     // s2[2j]    (row B)

        // shift queues (compile-time names -> pure v_mov, no scratch)
        tA0 = tA2; tA1 = tA3; tA2 = tA4; tA3 = tA5; tA4 = tA6; tA5 = tA7;
        tA6 = sAA; tA7 = sBA;
        tB0 = tB2; tB1 = tB3; tB2 = tB4; tB3 = tB5; tB4 = tB6; tB5 = tB7;
        tB6 = sAB; tB7 = sBB;
        uA0 = uA2; uA1 = uA3; uA2 = uA4; uA3 = uA5; uA4 = uA6; uA5 = uA7;
        uB0 = uB2; uB1 = uB3; uB2 = uB4; uB3 = uB5; uB4 = uB6; uB5 = uB7;
        #pragma unroll
        for (int f = 0; f < HF; ++f) { rmA[f] = rp0A[f]; rcA[f] = rp1A[f];
                                       rmB[f] = rp0B[f]; rcB[f] = rp1B[f]; }
    }
    // after loop: rm=r[8], rc=r[9]; t0..t7 = s2[1..8] (per row)

    // -------- epilogue: y bursts early, wrap emits, full-row stores -------
    float4 YA0 = yrA[0], YA1 = yrA[1], YA2 = yrA[2], YA3 = yrA[3], YA4 = yrA[4],
           YA5 = yrA[5], YA6 = yrA[6], YA7 = yrA[7], YA8 = yrA[8], YA9 = yrA[9];
    float4 YB0 = yrB[0], YB1 = yrB[1], YB2 = yrB[2], YB3 = yrB[3], YB4 = yrB[4],
           YB5 = yrB[5], YB6 = yrB[6], YB7 = yrB[7], YB8 = yrB[8], YB9 = yrB[9];

    const float s9A = emit(rmA, rcA, r0A);           // s2[9] row A
    const float s0A = emit(rcA, r0A, r1A);           // s2[0] row A
    const float s9B = emit(rmB, rcB, r0B);           // s2[9] row B
    const float s0B = emit(rcB, r0B, r1B);           // s2[0] row B

    store_out(ogA, 0, s0A, tA0, YA0);
    store_out(ogA, 1, tA0, tA1, YA1);
    store_out(ogA, 2, tA1, tA2, YA2);
    store_out(ogA, 3, tA2, tA3, YA3);
    store_out(ogA, 4, tA3, tA4, YA4);
    store_out(ogA, 5, tA4, tA5, YA5);
    store_out(ogA, 6, tA5, tA6, YA6);
    store_out(ogA, 7, tA6, tA7, YA7);
    store_out(ogA, 8, tA7, s9A, YA8);
    store_out(ogA, 9, s9A, s0A, YA9);

    store_out(ogB, 0, s0B, tB0, YB0);
    store_out(ogB, 1, tB0, tB1, YB1);
    store_out(ogB, 2, tB1, tB2, YB2);
    store_out(ogB, 3, tB2, tB3, YB3);
    store_out(ogB, 4, tB3, tB4, YB4);
    store_out(ogB, 5, tB4, tB5, YB5);
    store_out(ogB, 6, tB5, tB6, YB6);
    store_out(ogB, 7, tB6, tB7, YB7);
    store_out(ogB, 8, tB7, s9B, YB8);
    store_out(ogB, 9, s9B, s0B, YB9);
}

extern "C" void kernel_launch(void* const* d_in, const int* in_sizes, int n_in,
                              void* d_out, int out_size, void* d_ws, size_t ws_size,
                              hipStream_t stream) {
    const float* x          = (const float*)d_in[0];
    const float* z          = (const float*)d_in[1];
    const float* y          = (const float*)d_in[2];
    const float* enc_rel_w  = (const float*)d_in[3];
    const float* enc_rel_b  = (const float*)d_in[4];
    const float* enc_root_w = (const float*)d_in[5];
    const float* pred_rel_w = (const float*)d_in[6];
    const float* pred_rel_b = (const float*)d_in[7];
    const float* pred_root_w= (const float*)d_in[8];
    const float* dec_rel_w  = (const float*)d_in[9];
    const float* dec_rel_b  = (const float*)d_in[10];
    const float* dec_root_w = (const float*)d_in[11];
    float* out = (float*)d_out;

    const int B = in_sizes[0] / ND;       // 524288, divisible by RPB
    const int blocks = B / RPB;           // 1024
    gnn_kernel<<<blocks, TPB, 0, stream>>>(
        x, z, y, enc_rel_w, enc_rel_b, enc_root_w,
        pred_rel_w, pred_rel_b, pred_root_w,
        dec_rel_w, dec_rel_b, dec_root_w, out, B);
}

// Round 7
// 406.120 us; speedup vs baseline: 1.0944x; 1.0944x over previous
//
#include <hip/hip_runtime.h>

// nnmodel_35708358099045 R10: R9 (two rows/thread, cross-row pipelined)
// WITHOUT the VGPR cap that corrupted R8/R9.
// Discovery: on this hipcc, __launch_bounds__(256,k) caps VGPR at 256/k:
//   R8 (256,4) -> VGPR 64 (needed ~88): remat/spill, FETCH +24 MB.
//   R9 (256,3) -> VGPR 84 (needed ~150): heavy spill, WRITE 86->120 MB,
//   FETCH 205->320 MB -- the entire R9 regression.
// This run: __launch_bounds__(256) only; expected VGPR ~130-170, no spill.
// Mechanism under test (unchanged from R9): per iter 8 z-line loads issue
// back-to-back; row-A compute (~1000 cy) covers row-B loads; row-B computes
// wait-free. Doubles per-wave MLP, makes HBM demand continuous (R6 showed
// 3.4 TB/s sustained under continuous demand vs R7's 2.0 phase-aligned).
// FP order per row identical to R5-R9 -> bit-identical output.

#define HN 10
#define ND 40
#define HF 8
#define TPB 256
#define RPT 2              // rows per thread
#define RPB (TPB * RPT)    // 512 rows per block

__global__ __launch_bounds__(TPB) void gnn_kernel(
    const float* __restrict__ x,          // [B, 40]
    const float* __restrict__ z,          // [B, 10, 8]
    const float* __restrict__ y,          // [B, 40]
    const float* __restrict__ enc_rel_w,  // [8, 1]
    const float* __restrict__ enc_rel_b,  // [8]
    const float* __restrict__ enc_root_w, // [8, 8]
    const float* __restrict__ pred_rel_w, // [8, 8]
    const float* __restrict__ pred_rel_b, // [8]
    const float* __restrict__ pred_root_w,// [8, 8]
    const float* __restrict__ dec_rel_w,  // [1, 8]
    const float* __restrict__ dec_rel_b,  // [1]
    const float* __restrict__ dec_root_w, // [1, 1]
    float* __restrict__ out,              // [B, 40]
    int B)
{
    const long long eA = (long long)blockIdx.x * RPB + threadIdx.x;
    const long long eB = eA + TPB;

    const float w = 0.8948393168143698f;  // exp(-(1/3)^2) as fp32

    const float4* xrA = (const float4*)(x + eA * ND);
    const float4* zrA = (const float4*)(z + eA * (HN * HF));
    const float4* yrA = (const float4*)(y + eA * ND);
    float4*       ogA = (float4*)(out + eA * ND);
    const float4* xrB = (const float4*)(x + eB * ND);
    const float4* zrB = (const float4*)(z + eB * (HN * HF));
    const float4* yrB = (const float4*)(y + eB * ND);
    float4*       ogB = (float4*)(out + eB * ND);

    const float drb   = dec_rel_b[0];
    const float droot = dec_root_w[0];

    // encoder GraphConv row: r = relu(agg*erw + erb + z . enc_root_w)
    auto enc_row = [&](float aggv, float4 v0, float4 v1, float (&r)[HF]) {
        float zrow[HF] = {v0.x, v0.y, v0.z, v0.w, v1.x, v1.y, v1.z, v1.w};
        #pragma unroll
        for (int f = 0; f < HF; ++f) {
            float acc = aggv * enc_rel_w[f] + enc_rel_b[f];
            #pragma unroll
            for (int g = 0; g < HF; ++g)
                acc += zrow[g] * enc_root_w[f * HF + g];
            r[f] = fmaxf(acc, 0.0f);
        }
    };

    // predictor + decoder row-dot for center rc with neighbors rm, rp
    auto emit = [&](const float (&rm)[HF], const float (&rc)[HF],
                    const float (&rp)[HF]) -> float {
        float a2[HF];
        #pragma unroll
        for (int f = 0; f < HF; ++f)
            a2[f] = rc[f] + w * (rm[f] + rp[f]);
        float s = 0.0f;
        #pragma unroll
        for (int f = 0; f < HF; ++f) {
            float acc = pred_rel_b[f];
            #pragma unroll
            for (int g = 0; g < HF; ++g)
                acc += a2[g] * pred_rel_w[f * HF + g];
            #pragma unroll
            for (int g = 0; g < HF; ++g)
                acc += rc[g] * pred_root_w[f * HF + g];
            s += fmaxf(acc, 0.0f) * dec_rel_w[f];
        }
        return s;
    };

    auto store_out = [&](float4* og, int idx, float sa, float sb, float4 yv) {
        const float pair = sa + sb + drb;
        float4 o;
        o.x = (sa + drb) + yv.x * droot;
        o.y = pair       + yv.y * droot;
        o.z = pair       + yv.z * droot;
        o.w = (sb + drb) + yv.w * droot;
        og[idx] = o;
    };

    // -------- prologue: one big burst (xA, xB, zA line0, zB line0) --------
    float4 XA0 = xrA[0], XA1 = xrA[1], XA2 = xrA[2], XA3 = xrA[3], XA4 = xrA[4],
           XA5 = xrA[5], XA6 = xrA[6], XA7 = xrA[7], XA8 = xrA[8], XA9 = xrA[9];
    float4 XB0 = xrB[0], XB1 = xrB[1], XB2 = xrB[2], XB3 = xrB[3], XB4 = xrB[4],
           XB5 = xrB[5], XB6 = xrB[6], XB7 = xrB[7], XB8 = xrB[8], XB9 = xrB[9];
    float4 zqA0 = zrA[0], zqA1 = zrA[1], zqA2 = zrA[2], zqA3 = zrA[3];
    float4 zqB0 = zrB[0], zqB1 = zrB[1], zqB2 = zrB[2], zqB3 = zrB[3];

    // aggs row A (frees XA), FP order as R5-R9
    const float aA0 = XA9.y + XA9.z + XA9.w + XA0.x + XA0.y + XA0.z;
    const float aA1 = XA0.y + XA0.z + XA0.w + XA1.x + XA1.y + XA1.z;
    const float aA2 = XA1.y + XA1.z + XA1.w + XA2.x + XA2.y + XA2.z;
    const float aA3 = XA2.y + XA2.z + XA2.w + XA3.x + XA3.y + XA3.z;
    const float aA4 = XA3.y + XA3.z + XA3.w + XA4.x + XA4.y + XA4.z;
    const float aA5 = XA4.y + XA4.z + XA4.w + XA5.x + XA5.y + XA5.z;
    const float aA6 = XA5.y + XA5.z + XA5.w + XA6.x + XA6.y + XA6.z;
    const float aA7 = XA6.y + XA6.z + XA6.w + XA7.x + XA7.y + XA7.z;
    const float aA8 = XA7.y + XA7.z + XA7.w + XA8.x + XA8.y + XA8.z;
    const float aA9 = XA8.y + XA8.z + XA8.w + XA9.x + XA9.y + XA9.z;
    // aggs row B (frees XB)
    const float aB0 = XB9.y + XB9.z + XB9.w + XB0.x + XB0.y + XB0.z;
    const float aB1 = XB0.y + XB0.z + XB0.w + XB1.x + XB1.y + XB1.z;
    const float aB2 = XB1.y + XB1.z + XB1.w + XB2.x + XB2.y + XB2.z;
    const float aB3 = XB2.y + XB2.z + XB2.w + XB3.x + XB3.y + XB3.z;
    const float aB4 = XB3.y + XB3.z + XB3.w + XB4.x + XB4.y + XB4.z;
    const float aB5 = XB4.y + XB4.z + XB4.w + XB5.x + XB5.y + XB5.z;
    const float aB6 = XB5.y + XB5.z + XB5.w + XB6.x + XB6.y + XB6.z;
    const float aB7 = XB6.y + XB6.z + XB6.w + XB7.x + XB7.y + XB7.z;
    const float aB8 = XB7.y + XB7.z + XB7.w + XB8.x + XB8.y + XB8.z;
    const float aB9 = XB8.y + XB8.z + XB8.w + XB9.x + XB9.y + XB9.z;

    // agg queues (nodes 2..9), shifted by 2 per iteration
    float uA0 = aA2, uA1 = aA3, uA2 = aA4, uA3 = aA5,
          uA4 = aA6, uA5 = aA7, uA6 = aA8, uA7 = aA9;
    float uB0 = aB2, uB1 = aB3, uB2 = aB4, uB3 = aB5,
          uB4 = aB6, uB5 = aB7, uB6 = aB8, uB7 = aB9;

    float r0A[HF], r1A[HF], r0B[HF], r1B[HF];
    enc_row(aA0, zqA0, zqA1, r0A);
    enc_row(aA1, zqA2, zqA3, r1A);
    enc_row(aB0, zqB0, zqB1, r0B);
    enc_row(aB1, zqB2, zqB3, r1B);

    float rmA[HF], rcA[HF], rmB[HF], rcB[HF];
    #pragma unroll
    for (int f = 0; f < HF; ++f) { rmA[f] = r0A[f]; rcA[f] = r1A[f];
                                   rmB[f] = r0B[f]; rcB[f] = r1B[f]; }

    // s2[1..8] shift queues
    float tA0 = 0.f, tA1 = 0.f, tA2 = 0.f, tA3 = 0.f,
          tA4 = 0.f, tA5 = 0.f, tA6 = 0.f, tA7 = 0.f;
    float tB0 = 0.f, tB1 = 0.f, tB2 = 0.f, tB3 = 0.f,
          tB4 = 0.f, tB5 = 0.f, tB6 = 0.f, tB7 = 0.f;

    // -------- loop: j=1..4, nodes (2j,2j+1) for both rows ----------------
    // Issue both rows' z-lines back-to-back; row-A compute covers row-B's
    // loads in flight; row-B compute runs wait-free.
    #pragma unroll 1
    for (int j = 1; j <= 4; ++j) {
        float4 qA0 = zrA[4*j + 0], qA1 = zrA[4*j + 1],
               qA2 = zrA[4*j + 2], qA3 = zrA[4*j + 3];
        float4 qB0 = zrB[4*j + 0], qB1 = zrB[4*j + 1],
               qB2 = zrB[4*j + 2], qB3 = zrB[4*j + 3];

        float rp0A[HF], rp1A[HF];
        enc_row(uA0, qA0, qA1, rp0A);                // node 2j   (row A)
        enc_row(uA1, qA2, qA3, rp1A);                // node 2j+1 (row A)
        const float sAA = emit(rmA, rcA, rp0A);      // s2[2j-1]  (row A)
        const float sBA = emit(rcA, rp0A, rp1A);     // s2[2j]    (row A)

        float rp0B[HF], rp1B[HF];
        enc_row(uB0, qB0, qB1, rp0B);                // node 2j   (row B)
        enc_row(uB1, qB2, qB3, rp1B);                // node 2j+1 (row B)
        const float sAB = emit(rmB, rcB, rp0B);      // s2[2j-1]  (row B)
        const float sBB = emit(rcB, rp0B, rp1B);     // s2[2j]    (row B)

        // shift queues (compile-time names -> pure v_mov, no scratch)
        tA0 = tA2; tA1 = tA3; tA2 = tA4; tA3 = tA5; tA4 = tA6; tA5 = tA7;
        tA6 = sAA; tA7 = sBA;
        tB0 = tB2; tB1 = tB3; tB2 = tB4; tB3 = tB5; tB4 = tB6; tB5 = tB7;
        tB6 = sAB; tB7 = sBB;
        uA0 = uA2; uA1 = uA3; uA2 = uA4; uA3 = uA5; uA4 = uA6; uA5 = uA7;
        uB0 = uB2; uB1 = uB3; uB2 = uB4; uB3 = uB5; uB4 = uB6; uB5 = uB7;
        #pragma unroll
        for (int f = 0; f < HF; ++f) { rmA[f] = rp0A[f]; rcA[f] = rp1A[f];
                                       rmB[f] = rp0B[f]; rcB[f] = rp1B[f]; }
    }
    // after loop: rm=r[8], rc=r[9]; t0..t7 = s2[1..8] (per row)

    // -------- epilogue: y bursts early, wrap emits, full-row stores -------
    float4 YA0 = yrA[0], YA1 = yrA[1], YA2 = yrA[2], YA3 = yrA[3], YA4 = yrA[4],
           YA5 = yrA[5], YA6 = yrA[6], YA7 = yrA[7], YA8 = yrA[8], YA9 = yrA[9];
    float4 YB0 = yrB[0], YB1 = yrB[1], YB2 = yrB[2], YB3 = yrB[3], YB4 = yrB[4],
           YB5 = yrB[5], YB6 = yrB[6], YB7 = yrB[7], YB8 = yrB[8], YB9 = yrB[9];

    const float s9A = emit(rmA, rcA, r0A);           // s2[9] row A
    const float s0A = emit(rcA, r0A, r1A);           // s2[0] row A
    const float s9B = emit(rmB, rcB, r0B);           // s2[9] row B
    const float s0B = emit(rcB, r0B, r1B);           // s2[0] row B

    store_out(ogA, 0, s0A, tA0, YA0);
    store_out(ogA, 1, tA0, tA1, YA1);
    store_out(ogA, 2, tA1, tA2, YA2);
    store_out(ogA, 3, tA2, tA3, YA3);
    store_out(ogA, 4, tA3, tA4, YA4);
    store_out(ogA, 5, tA4, tA5, YA5);
    store_out(ogA, 6, tA5, tA6, YA6);
    store_out(ogA, 7, tA6, tA7, YA7);
    store_out(ogA, 8, tA7, s9A, YA8);
    store_out(ogA, 9, s9A, s0A, YA9);

    store_out(ogB, 0, s0B, tB0, YB0);
    store_out(ogB, 1, tB0, tB1, YB1);
    store_out(ogB, 2, tB1, tB2, YB2);
    store_out(ogB, 3, tB2, tB3, YB3);
    store_out(ogB, 4, tB3, tB4, YB4);
    store_out(ogB, 5, tB4, tB5, YB5);
    store_out(ogB, 6, tB5, tB6, YB6);
    store_out(ogB, 7, tB6, tB7, YB7);
    store_out(ogB, 8, tB7, s9B, YB8);
    store_out(ogB, 9, s9B, s0B, YB9);
}

extern "C" void kernel_launch(void* const* d_in, const int* in_sizes, int n_in,
                              void* d_out, int out_size, void* d_ws, size_t ws_size,
                              hipStream_t stream) {
    const float* x          = (const float*)d_in[0];
    const float* z          = (const float*)d_in[1];
    const float* y          = (const float*)d_in[2];
    const float* enc_rel_w  = (const float*)d_in[3];
    const float* enc_rel_b  = (const float*)d_in[4];
    const float* enc_root_w = (const float*)d_in[5];
    const float* pred_rel_w = (const float*)d_in[6];
    const float* pred_rel_b = (const float*)d_in[7];
    const float* pred_root_w= (const float*)d_in[8];
    const float* dec_rel_w  = (const float*)d_in[9];
    const float* dec_rel_b  = (const float*)d_in[10];
    const float* dec_root_w = (const float*)d_in[11];
    float* out = (float*)d_out;

    const int B = in_sizes[0] / ND;       // 524288, divisible by RPB
    const int blocks = B / RPB;           // 1024
    gnn_kernel<<<blocks, TPB, 0, stream>>>(
        x, z, y, enc_rel_w, enc_rel_b, enc_root_w,
        pred_rel_w, pred_rel_b, pred_root_w,
        dec_rel_w, dec_rel_b, dec_root_w, out, B);
}

// Round 8
// 401.140 us; speedup vs baseline: 1.1080x; 1.0124x over previous
//
#include <hip/hip_runtime.h>

// nnmodel_35708358099045 R11: R8 (1-deep z-line software pipeline) WITHOUT
// the VGPR cap that invalidated R8's measurement.
// History: R8 ran with __launch_bounds__(256,4) -> hipcc hard-caps VGPR at
// 64 while the pipelined loop needs ~88 -> remat/reload (FETCH +24 MB,
// VALUBusy down, 153 us). R9/R10 showed (256,3)->84 caused outright spill,
// and uncapped 2-row (R10, VGPR 128) was clean but didn't help -> cross-row
// MLP refuted. The one still-untested mechanism from the burst/wait model:
// per-iteration prefetch of the NEXT z line so the ~1000-cy enc+emit body
// covers its latency. This run: identical structure to R8, launch bounds
// (256) only. Expect VGPR 88-104, FETCH ~205 MB, WRITE ~84 MB.
// FP order identical to R5-R10 -> bit-identical output.

#define HN 10
#define ND 40
#define HF 8
#define TPB 256

__global__ __launch_bounds__(TPB) void gnn_kernel(
    const float* __restrict__ x,          // [B, 40]
    const float* __restrict__ z,          // [B, 10, 8]
    const float* __restrict__ y,          // [B, 40]
    const float* __restrict__ enc_rel_w,  // [8, 1]
    const float* __restrict__ enc_rel_b,  // [8]
    const float* __restrict__ enc_root_w, // [8, 8]
    const float* __restrict__ pred_rel_w, // [8, 8]
    const float* __restrict__ pred_rel_b, // [8]
    const float* __restrict__ pred_root_w,// [8, 8]
    const float* __restrict__ dec_rel_w,  // [1, 8]
    const float* __restrict__ dec_rel_b,  // [1]
    const float* __restrict__ dec_root_w, // [1, 1]
    float* __restrict__ out,              // [B, 40]
    int B)
{
    const long long e = (long long)blockIdx.x * TPB + threadIdx.x;

    const float w = 0.8948393168143698f;  // exp(-(1/3)^2) as fp32

    const float4* xr = (const float4*)(x + e * ND);        // 10 float4
    const float4* zr = (const float4*)(z + e * (HN * HF)); // 20 float4
    const float4* yr = (const float4*)(y + e * ND);        // 10 float4
    float4*       og = (float4*)(out + e * ND);            // 10 float4

    const float drb   = dec_rel_b[0];
    const float droot = dec_root_w[0];

    // encoder GraphConv row: r = relu(agg*erw + erb + z . enc_root_w)
    auto enc_row = [&](float aggv, float4 v0, float4 v1, float (&r)[HF]) {
        float zrow[HF] = {v0.x, v0.y, v0.z, v0.w, v1.x, v1.y, v1.z, v1.w};
        #pragma unroll
        for (int f = 0; f < HF; ++f) {
            float acc = aggv * enc_rel_w[f] + enc_rel_b[f];
            #pragma unroll
            for (int g = 0; g < HF; ++g)
                acc += zrow[g] * enc_root_w[f * HF + g];
            r[f] = fmaxf(acc, 0.0f);
        }
    };

    // predictor + decoder row-dot for center rc with neighbors rm, rp
    auto emit = [&](const float (&rm)[HF], const float (&rc)[HF],
                    const float (&rp)[HF]) -> float {
        float a2[HF];
        #pragma unroll
        for (int f = 0; f < HF; ++f)
            a2[f] = rc[f] + w * (rm[f] + rp[f]);
        float s = 0.0f;
        #pragma unroll
        for (int f = 0; f < HF; ++f) {
            float acc = pred_rel_b[f];
            #pragma unroll
            for (int g = 0; g < HF; ++g)
                acc += a2[g] * pred_rel_w[f * HF + g];
            #pragma unroll
            for (int g = 0; g < HF; ++g)
                acc += rc[g] * pred_root_w[f * HF + g];
            s += fmaxf(acc, 0.0f) * dec_rel_w[f];
        }
        return s;
    };

    auto store_out = [&](int idx, float sa, float sb, float4 yv) {
        const float pair = sa + sb + drb;
        float4 o;
        o.x = (sa + drb) + yv.x * droot;
        o.y = pair       + yv.y * droot;
        o.z = pair       + yv.z * droot;
        o.w = (sb + drb) + yv.w * droot;
        og[idx] = o;
    };

    // -------- prologue: x fully (hot lines), aggs, nodes 0-1 --------
    float4 X0 = xr[0], X1 = xr[1], X2 = xr[2], X3 = xr[3], X4 = xr[4],
           X5 = xr[5], X6 = xr[6], X7 = xr[7], X8 = xr[8], X9 = xr[9];
    // agg[j] = X[j-1].y+.z+.w + X[j].x+.y+.z (cyclic), FP order as R5-R10
    const float a0 = X9.y + X9.z + X9.w + X0.x + X0.y + X0.z;
    const float a1 = X0.y + X0.z + X0.w + X1.x + X1.y + X1.z;
    const float a2v= X1.y + X1.z + X1.w + X2.x + X2.y + X2.z;
    const float a3 = X2.y + X2.z + X2.w + X3.x + X3.y + X3.z;
    const float a4 = X3.y + X3.z + X3.w + X4.x + X4.y + X4.z;
    const float a5 = X4.y + X4.z + X4.w + X5.x + X5.y + X5.z;
    const float a6 = X5.y + X5.z + X5.w + X6.x + X6.y + X6.z;
    const float a7 = X6.y + X6.z + X6.w + X7.x + X7.y + X7.z;
    const float a8 = X7.y + X7.z + X7.w + X8.x + X8.y + X8.z;
    const float a9 = X8.y + X8.z + X8.w + X9.x + X9.y + X9.z;

    // agg queue for loop (nodes 2..9), shifted by 2 per iteration
    float u0 = a2v, u1 = a3, u2 = a4, u3 = a5,
          u4 = a6,  u5 = a7, u6 = a8, u7 = a9;

    // z line 0 (nodes 0,1) + prefetch of line 1 (nodes 2,3) BEFORE the
    // enc_rows, so line-1 latency hides under the two prologue enc_rows.
    float4 zc0, zc1, zc2, zc3;   // current line (consumed this iter)
    float r0s[HF], r1s[HF];
    {
        float4 zq0 = zr[0], zq1 = zr[1], zq2 = zr[2], zq3 = zr[3];
        zc0 = zr[4]; zc1 = zr[5]; zc2 = zr[6]; zc3 = zr[7];   // line j=1
        enc_row(a0, zq0, zq1, r0s);
        enc_row(a1, zq2, zq3, r1s);
    }

    float rm[HF], rc[HF];
    #pragma unroll
    for (int f = 0; f < HF; ++f) { rm[f] = r0s[f]; rc[f] = r1s[f]; }

    // s2[1..8] shift queue
    float t0 = 0.f, t1 = 0.f, t2 = 0.f, t3 = 0.f,
          t4 = 0.f, t5 = 0.f, t6 = 0.f, t7 = 0.f;

    // -------- loop: j=1..4, nodes (2j, 2j+1), pipelined z lines --------
    #pragma unroll 1
    for (int j = 1; j <= 4; ++j) {
        // prefetch next line (one 64 B line/lane, back-to-back issue)
        float4 zn0, zn1, zn2, zn3;
        if (j < 4) {
            zn0 = zr[4*j + 4]; zn1 = zr[4*j + 5];
            zn2 = zr[4*j + 6]; zn3 = zr[4*j + 7];
        }

        float rp0[HF], rp1[HF];
        enc_row(u0, zc0, zc1, rp0);                  // node 2j
        enc_row(u1, zc2, zc3, rp1);                  // node 2j+1

        const float sA = emit(rm, rc, rp0);          // s2[2j-1]
        const float sB = emit(rc, rp0, rp1);         // s2[2j]

        // shift queues (all compile-time names -> pure v_mov, no scratch)
        t0 = t2; t1 = t3; t2 = t4; t3 = t5; t4 = t6; t5 = t7;
        t6 = sA; t7 = sB;
        u0 = u2; u1 = u3; u2 = u4; u3 = u5; u4 = u6; u5 = u7;
        #pragma unroll
        for (int f = 0; f < HF; ++f) { rm[f] = rp0[f]; rc[f] = rp1[f]; }
        if (j < 4) { zc0 = zn0; zc1 = zn1; zc2 = zn2; zc3 = zn3; }
    }
    // after loop: rm=r[8], rc=r[9]; t0..t7 = s2[1..8]

    // -------- epilogue: y early (overlaps tail emits), wrap emits --------
    float4 Y0 = yr[0], Y1 = yr[1], Y2 = yr[2], Y3 = yr[3], Y4 = yr[4],
           Y5 = yr[5], Y6 = yr[6], Y7 = yr[7], Y8 = yr[8], Y9 = yr[9];

    const float s9 = emit(rm, rc, r0s);              // s2[9] = emit(r8,r9,r0)
    const float s0 = emit(rc, r0s, r1s);             // s2[0] = emit(r9,r0,r1)

    // straight-line full-row store: 10 full float4, back-to-back
    store_out(0, s0, t0, Y0);
    store_out(1, t0, t1, Y1);
    store_out(2, t1, t2, Y2);
    store_out(3, t2, t3, Y3);
    store_out(4, t3, t4, Y4);
    store_out(5, t4, t5, Y5);
    store_out(6, t5, t6, Y6);
    store_out(7, t6, t7, Y7);
    store_out(8, t7, s9, Y8);
    store_out(9, s9, s0, Y9);
}

extern "C" void kernel_launch(void* const* d_in, const int* in_sizes, int n_in,
                              void* d_out, int out_size, void* d_ws, size_t ws_size,
                              hipStream_t stream) {
    const float* x          = (const float*)d_in[0];
    const float* z          = (const float*)d_in[1];
    const float* y          = (const float*)d_in[2];
    const float* enc_rel_w  = (const float*)d_in[3];
    const float* enc_rel_b  = (const float*)d_in[4];
    const float* enc_root_w = (const float*)d_in[5];
    const float* pred_rel_w = (const float*)d_in[6];
    const float* pred_rel_b = (const float*)d_in[7];
    const float* pred_root_w= (const float*)d_in[8];
    const float* dec_rel_w  = (const float*)d_in[9];
    const float* dec_rel_b  = (const float*)d_in[10];
    const float* dec_root_w = (const float*)d_in[11];
    float* out = (float*)d_out;

    const int B = in_sizes[0] / ND;       // 524288, divisible by TPB
    const int blocks = B / TPB;
    gnn_kernel<<<blocks, TPB, 0, stream>>>(
        x, z, y, enc_rel_w, enc_rel_b, enc_root_w,
        pred_rel_w, pred_rel_b, pred_root_w,
        dec_rel_w, dec_rel_b, dec_root_w, out, B);
}

// Round 9
// 398.819 us; speedup vs baseline: 1.1144x; 1.0058x over previous
//
#include <hip/hip_runtime.h>

// nnmodel_35708358099045 R12: R7 loop + fully COALESCED global traffic via
// wave-private LDS transpose (no block barriers).
// Evidence: CU-side demand BW pins at ~3.4 TB/s across R3/R5/R6/R7/R10/R11
// (occupancy 3.5x, MLP 2x, refetch 5x all no-ops) -- every one of those
// kernels issues 64-line-divergent dwordx4 (one row per lane). m13's 6.29
// TB/s copy uses 16-line coalesced instructions. Per-instr service time:
// ours ~185 cy vs copy ~96 cy -> cost ~ lines/instr. Coalesced was only
// ever tried with barrier-phase kernels (R3/R4, occ-bound); never with the
// R7 loop. This kernel: lane l loads CONSECUTIVE float4s (16 lines/instr),
// wave-private LDS transpose (R4-proven lgkmcnt+sched_barrier, no
// __syncthreads), z staged line-by-line double-buffered with loads issued
// one iteration early. Math/FP order bit-identical to R5-R11.

#define HN 10
#define ND 40
#define HF 8
#define TPB 256
#define WLEN 64
#define ROW4 11   // padded row stride in float4 (x / out staging)
#define ZROW 5    // padded z-slice stride in float4

__global__ __launch_bounds__(TPB) void gnn_kernel(
    const float* __restrict__ x,          // [B, 40]
    const float* __restrict__ z,          // [B, 10, 8]
    const float* __restrict__ y,          // [B, 40]
    const float* __restrict__ enc_rel_w,  // [8, 1]
    const float* __restrict__ enc_rel_b,  // [8]
    const float* __restrict__ enc_root_w, // [8, 8]
    const float* __restrict__ pred_rel_w, // [8, 8]
    const float* __restrict__ pred_rel_b, // [8]
    const float* __restrict__ pred_root_w,// [8, 8]
    const float* __restrict__ dec_rel_w,  // [1, 8]
    const float* __restrict__ dec_rel_b,  // [1]
    const float* __restrict__ dec_root_w, // [1, 1]
    float* __restrict__ out,              // [B, 40]
    int B)
{
    __shared__ float4 lds4[TPB * ROW4];   // 45056 B: 704 float4 per wave
    const int t  = threadIdx.x;
    const int l  = t & 63;
    const int wv = t >> 6;
    const long long W = (long long)blockIdx.x * TPB + wv * WLEN; // wave row base
    float4* wl = lds4 + wv * (WLEN * ROW4);

    const float w = 0.8948393168143698f;  // exp(-(1/3)^2) as fp32

    const float4* xg4 = (const float4*)x;   // row r = 10 float4 at r*10
    const float4* zg4 = (const float4*)z;   // row r = 20 float4 at r*20
    const float4* yg4 = (const float4*)y;
    float4*       og4 = (float4*)out;

    const float drb   = dec_rel_b[0];
    const float droot = dec_root_w[0];

    auto enc_row = [&](float aggv, float4 v0, float4 v1, float (&r)[HF]) {
        float zrow[HF] = {v0.x, v0.y, v0.z, v0.w, v1.x, v1.y, v1.z, v1.w};
        #pragma unroll
        for (int f = 0; f < HF; ++f) {
            float acc = aggv * enc_rel_w[f] + enc_rel_b[f];
            #pragma unroll
            for (int g = 0; g < HF; ++g)
                acc += zrow[g] * enc_root_w[f * HF + g];
            r[f] = fmaxf(acc, 0.0f);
        }
    };

    auto emit = [&](const float (&rm)[HF], const float (&rc)[HF],
                    const float (&rp)[HF]) -> float {
        float a2[HF];
        #pragma unroll
        for (int f = 0; f < HF; ++f)
            a2[f] = rc[f] + w * (rm[f] + rp[f]);
        float s = 0.0f;
        #pragma unroll
        for (int f = 0; f < HF; ++f) {
            float acc = pred_rel_b[f];
            #pragma unroll
            for (int g = 0; g < HF; ++g)
                acc += a2[g] * pred_rel_w[f * HF + g];
            #pragma unroll
            for (int g = 0; g < HF; ++g)
                acc += rc[g] * pred_root_w[f * HF + g];
            s += fmaxf(acc, 0.0f) * dec_rel_w[f];
        }
        return s;
    };

    // ---- X phase: coalesced load (16 lines/instr) + LDS transpose ----
    float4 xv4[10];
    #pragma unroll
    for (int k = 0; k < 10; ++k) xv4[k] = xg4[W * 10 + l + 64 * k];
    // issue z line-0 loads now (coalesced: 16 consecutive rows x 1 full line
    // per instruction), so they fly during the x transpose + aggs
    float4 zt[4];
    #pragma unroll
    for (int k = 0; k < 4; ++k) {
        int i = l + 64 * k; int r = i >> 2, m = i & 3;
        zt[k] = zg4[(W + r) * 20 + m];               // line j=0
    }
    #pragma unroll
    for (int k = 0; k < 10; ++k) {
        int i = l + 64 * k; int r = i / 10, q = i - r * 10;
        wl[r * ROW4 + q] = xv4[k];
    }
    asm volatile("s_waitcnt lgkmcnt(0)" ::: "memory");
    __builtin_amdgcn_sched_barrier(0);
    float xv[ND];
    #pragma unroll
    for (int k = 0; k < 10; ++k) {
        float4 v = wl[l * ROW4 + k];                 // conflict-free b128 (R3)
        xv[4*k] = v.x; xv[4*k+1] = v.y; xv[4*k+2] = v.z; xv[4*k+3] = v.w;
    }
    // aggs, FP order identical to R5-R11
    const float a0 = xv[37] + xv[38] + xv[39] + xv[0] + xv[1] + xv[2];
    const float a1 = xv[1]  + xv[2]  + xv[3]  + xv[4] + xv[5] + xv[6];
    const float a2v= xv[5]  + xv[6]  + xv[7]  + xv[8] + xv[9] + xv[10];
    const float a3 = xv[9]  + xv[10] + xv[11] + xv[12]+ xv[13]+ xv[14];
    const float a4 = xv[13] + xv[14] + xv[15] + xv[16]+ xv[17]+ xv[18];
    const float a5 = xv[17] + xv[18] + xv[19] + xv[20]+ xv[21]+ xv[22];
    const float a6 = xv[21] + xv[22] + xv[23] + xv[24]+ xv[25]+ xv[26];
    const float a7 = xv[25] + xv[26] + xv[27] + xv[28]+ xv[29]+ xv[30];
    const float a8 = xv[29] + xv[30] + xv[31] + xv[32]+ xv[33]+ xv[34];
    const float a9 = xv[33] + xv[34] + xv[35] + xv[36]+ xv[37]+ xv[38];

    float u0 = a2v, u1 = a3, u2 = a4, u3 = a5,
          u4 = a6,  u5 = a7, u6 = a8, u7 = a9;

    // ---- z iter 0 (peeled): write line0 -> buf0, issue line1, consume ----
    // x-LDS is dead (xv extracted). buf0 = wl[0..319], buf1 = wl[320..639].
    #pragma unroll
    for (int k = 0; k < 4; ++k) {
        int i = l + 64 * k; int r = i >> 2, m = i & 3;
        wl[r * ZROW + m] = zt[k];                    // buf0
    }
    #pragma unroll
    for (int k = 0; k < 4; ++k) {
        int i = l + 64 * k; int r = i >> 2, m = i & 3;
        zt[k] = zg4[(W + r) * 20 + 4 + m];           // line j=1 in flight
    }
    asm volatile("s_waitcnt lgkmcnt(0)" ::: "memory");
    __builtin_amdgcn_sched_barrier(0);
    float r0s[HF], r1s[HF];
    {
        float4 q0 = wl[l * ZROW + 0], q1 = wl[l * ZROW + 1],
               q2 = wl[l * ZROW + 2], q3 = wl[l * ZROW + 3];
        enc_row(a0, q0, q1, r0s);
        enc_row(a1, q2, q3, r1s);
    }
    float rm[HF], rc[HF];
    #pragma unroll
    for (int f = 0; f < HF; ++f) { rm[f] = r0s[f]; rc[f] = r1s[f]; }

    float t0 = 0.f, t1 = 0.f, t2 = 0.f, t3 = 0.f,
          t4 = 0.f, t5 = 0.f, t6 = 0.f, t7 = 0.f;

    // ---- loop j=1..4: write line j (dbuf), issue line j+1, consume ----
    #pragma unroll 1
    for (int j = 1; j <= 4; ++j) {
        float4* bw = wl + (j & 1) * (WLEN * ZROW);
        #pragma unroll
        for (int k = 0; k < 4; ++k) {
            int i = l + 64 * k; int r = i >> 2, m = i & 3;
            bw[r * ZROW + m] = zt[k];                // vmcnt-waits line j
        }
        if (j < 4) {
            #pragma unroll
            for (int k = 0; k < 4; ++k) {
                int i = l + 64 * k; int r = i >> 2, m = i & 3;
                zt[k] = zg4[(W + r) * 20 + 4 * (j + 1) + m];  // next line
            }
        }
        asm volatile("s_waitcnt lgkmcnt(0)" ::: "memory");
        __builtin_amdgcn_sched_barrier(0);
        float4 q0 = bw[l * ZROW + 0], q1 = bw[l * ZROW + 1],
               q2 = bw[l * ZROW + 2], q3 = bw[l * ZROW + 3];

        float rp0[HF], rp1[HF];
        enc_row(u0, q0, q1, rp0);                    // node 2j
        enc_row(u1, q2, q3, rp1);                    // node 2j+1
        const float sA = emit(rm, rc, rp0);          // s2[2j-1]
        const float sB = emit(rc, rp0, rp1);         // s2[2j]

        t0 = t2; t1 = t3; t2 = t4; t3 = t5; t4 = t6; t5 = t7;
        t6 = sA; t7 = sB;
        u0 = u2; u1 = u3; u2 = u4; u3 = u5; u4 = u6; u5 = u7;
        #pragma unroll
        for (int f = 0; f < HF; ++f) { rm[f] = rp0[f]; rc[f] = rp1[f]; }
    }
    // rm=r[8], rc=r[9]; t0..t7 = s2[1..8]

    // ---- epilogue: y coalesced (issued early), wrap emits, staged out ----
    float4 yv4[10];
    #pragma unroll
    for (int k = 0; k < 10; ++k) yv4[k] = yg4[W * 10 + l + 64 * k];

    const float s9 = emit(rm, rc, r0s);              // s2[9]
    const float s0 = emit(rc, r0s, r1s);             // s2[0]

    // out partials into 11-pad layout (z bufs dead)
    asm volatile("s_waitcnt lgkmcnt(0)" ::: "memory");
    __builtin_amdgcn_sched_barrier(0);
    {
        // s2[0]=s0, s2[1..8]=t0..t7, s2[9]=s9; pair k uses (s2[k], s2[k+1])
        float sa[10] = {s0, t0, t1, t2, t3, t4, t5, t6, t7, s9};
        float sb[10] = {t0, t1, t2, t3, t4, t5, t6, t7, s9, s0};
        #pragma unroll
        for (int k = 0; k < 10; ++k) {
            const float pair = sa[k] + sb[k] + drb;
            float4 vo;
            vo.x = sa[k] + drb;
            vo.y = pair;
            vo.z = pair;
            vo.w = sb[k] + drb;
            wl[l * ROW4 + k] = vo;                   // conflict-free b128
        }
    }
    asm volatile("s_waitcnt lgkmcnt(0)" ::: "memory");
    __builtin_amdgcn_sched_barrier(0);
    // drain: coalesced full-line stores (16 lines/instr)
    #pragma unroll
    for (int k = 0; k < 10; ++k) {
        int i = l + 64 * k; int e2 = i / 10, q = i - e2 * 10;
        float4 p = wl[e2 * ROW4 + q];                // near-sequential reads
        float4 vy = yv4[k];
        p.x += vy.x * droot;
        p.y += vy.y * droot;
        p.z += vy.z * droot;
        p.w += vy.w * droot;
        og4[W * 10 + i] = p;
    }
}

extern "C" void kernel_launch(void* const* d_in, const int* in_sizes, int n_in,
                              void* d_out, int out_size, void* d_ws, size_t ws_size,
                              hipStream_t stream) {
    const float* x          = (const float*)d_in[0];
    const float* z          = (const float*)d_in[1];
    const float* y          = (const float*)d_in[2];
    const float* enc_rel_w  = (const float*)d_in[3];
    const float* enc_rel_b  = (const float*)d_in[4];
    const float* enc_root_w = (const float*)d_in[5];
    const float* pred_rel_w = (const float*)d_in[6];
    const float* pred_rel_b = (const float*)d_in[7];
    const float* pred_root_w= (const float*)d_in[8];
    const float* dec_rel_w  = (const float*)d_in[9];
    const float* dec_rel_b  = (const float*)d_in[10];
    const float* dec_root_w = (const float*)d_in[11];
    float* out = (float*)d_out;

    const int B = in_sizes[0] / ND;       // 524288, divisible by TPB
    const int blocks = B / TPB;           // 2048
    gnn_kernel<<<blocks, TPB, 0, stream>>>(
        x, z, y, enc_rel_w, enc_rel_b, enc_root_w,
        pred_rel_w, pred_rel_b, pred_root_w,
        dec_rel_w, dec_rel_b, dec_root_w, out, B);
}